// Round 9
// baseline (578.698 us; speedup 1.0000x reference)
//
#include <hip/hip_runtime.h>
#include <cmath>

#define D 128
#define HID 64

__device__ __forceinline__ float silu_f(float x) { return x / (1.0f + expf(-x)); }

__device__ __forceinline__ float4 fma4(float a, float4 w, float4 c) {
    c.x = fmaf(a, w.x, c.x); c.y = fmaf(a, w.y, c.y);
    c.z = fmaf(a, w.z, c.z); c.w = fmaf(a, w.w, c.w);
    return c;
}
__device__ __forceinline__ float4 silu4(float4 v) {
    v.x = silu_f(v.x); v.y = silu_f(v.y); v.z = silu_f(v.z); v.w = silu_f(v.w);
    return v;
}
__device__ __forceinline__ float dot4(float4 a, float4 b) {
    return fmaf(a.x, b.x, fmaf(a.y, b.y, fmaf(a.z, b.z, a.w * b.w)));
}

// order-preserving float <-> uint encode for atomicMax on floats
__device__ __forceinline__ unsigned fenc(float f) {
    unsigned u = __float_as_uint(f);
    return (u & 0x80000000u) ? ~u : (u | 0x80000000u);
}
__device__ __forceinline__ float fdec(unsigned e) {
    unsigned u = (e & 0x80000000u) ? (e & 0x7FFFFFFFu) : ~e;
    return __uint_as_float(u);
}

#define ACC16(xv, wp) { const float4* _w4 = reinterpret_cast<const float4*>(wp); \
    h0  = fma4(xv, _w4[0],  h0);  h1  = fma4(xv, _w4[1],  h1);  \
    h2  = fma4(xv, _w4[2],  h2);  h3  = fma4(xv, _w4[3],  h3);  \
    h4  = fma4(xv, _w4[4],  h4);  h5  = fma4(xv, _w4[5],  h5);  \
    h6  = fma4(xv, _w4[6],  h6);  h7  = fma4(xv, _w4[7],  h7);  \
    h8  = fma4(xv, _w4[8],  h8);  h9  = fma4(xv, _w4[9],  h9);  \
    h10 = fma4(xv, _w4[10], h10); h11 = fma4(xv, _w4[11], h11); \
    h12 = fma4(xv, _w4[12], h12); h13 = fma4(xv, _w4[13], h13); \
    h14 = fma4(xv, _w4[14], h14); h15 = fma4(xv, _w4[15], h15); }

#define INIT16(bp) { const float4* _b4 = reinterpret_cast<const float4*>(bp); \
    h0 = _b4[0]; h1 = _b4[1]; h2 = _b4[2]; h3 = _b4[3]; \
    h4 = _b4[4]; h5 = _b4[5]; h6 = _b4[6]; h7 = _b4[7]; \
    h8 = _b4[8]; h9 = _b4[9]; h10 = _b4[10]; h11 = _b4[11]; \
    h12 = _b4[12]; h13 = _b4[13]; h14 = _b4[14]; h15 = _b4[15]; }

#define SILU16() { h0 = silu4(h0); h1 = silu4(h1); h2 = silu4(h2); h3 = silu4(h3); \
    h4 = silu4(h4); h5 = silu4(h5); h6 = silu4(h6); h7 = silu4(h7); \
    h8 = silu4(h8); h9 = silu4(h9); h10 = silu4(h10); h11 = silu4(h11); \
    h12 = silu4(h12); h13 = silu4(h13); h14 = silu4(h14); h15 = silu4(h15); }

// serial silu-dot over 4 units
__device__ __forceinline__ float accdot(float4 h, float4 w, float act) {
    act = fmaf(silu_f(h.x), w.x, act);
    act = fmaf(silu_f(h.y), w.y, act);
    act = fmaf(silu_f(h.z), w.z, act);
    act = fmaf(silu_f(h.w), w.w, act);
    return act;
}

// ---- protection net: 4 lanes/node split-hid, full pw1 in LDS, 64 nodes/block ----
__global__ __launch_bounds__(256) void k_protect(
    const float* __restrict__ states, const float* __restrict__ caps,
    const float* __restrict__ pw1, const float* __restrict__ pb1,
    const float* __restrict__ pw2, const float* __restrict__ pb2,
    unsigned* __restrict__ mask, unsigned* __restrict__ mlist,
    unsigned* __restrict__ counters, float* __restrict__ outmask, int N) {
    __shared__ float wl[129 * 64];                // 33 KB: all of pw1 (incl. capacity row)
    unsigned tid = threadIdx.x;
    {   // stage 8256 floats = 2064 float4, coalesced
        const float4* s4 = reinterpret_cast<const float4*>(pw1);
        float4* d4 = reinterpret_cast<float4*>(wl);
#pragma unroll
        for (int q = 0; q < 9; ++q) {
            unsigned idx = tid + q * 256u;
            if (idx < 2064u) d4[idx] = s4[idx];
        }
    }
    __syncthreads();
    unsigned nl = tid >> 2, g = tid & 3u;         // lane g owns hidden units [g*16, g*16+16)
    unsigned n = blockIdx.x * 64u + nl;
    bool active = n < (unsigned)N;
    unsigned nq = active ? n : (unsigned)(N - 1);
    const float4* row = reinterpret_cast<const float4*>(states + (size_t)nq * D);
    float4 a0, a1, a2, a3;
    { const float4* b4 = reinterpret_cast<const float4*>(pb1 + g * 16);
      a0 = b4[0]; a1 = b4[1]; a2 = b4[2]; a3 = b4[3]; }
    const float* wg = wl + g * 16;
#pragma unroll 1
    for (int kb = 0; kb < 32; ++kb) {
        float4 x = row[kb];
        const float* w = wg + (size_t)kb * 4 * HID;
        const float4* w0 = reinterpret_cast<const float4*>(w);
        const float4* w1 = reinterpret_cast<const float4*>(w + HID);
        const float4* w2q = reinterpret_cast<const float4*>(w + 2 * HID);
        const float4* w3q = reinterpret_cast<const float4*>(w + 3 * HID);
        a0 = fma4(x.x, w0[0], a0); a1 = fma4(x.x, w0[1], a1); a2 = fma4(x.x, w0[2], a2); a3 = fma4(x.x, w0[3], a3);
        a0 = fma4(x.y, w1[0], a0); a1 = fma4(x.y, w1[1], a1); a2 = fma4(x.y, w1[2], a2); a3 = fma4(x.y, w1[3], a3);
        a0 = fma4(x.z, w2q[0], a0); a1 = fma4(x.z, w2q[1], a1); a2 = fma4(x.z, w2q[2], a2); a3 = fma4(x.z, w2q[3], a3);
        a0 = fma4(x.w, w3q[0], a0); a1 = fma4(x.w, w3q[1], a1); a2 = fma4(x.w, w3q[2], a2); a3 = fma4(x.w, w3q[3], a3);
    }
    {   // capacity row (input dim 128)
        float xv = caps[nq];
        const float4* wc = reinterpret_cast<const float4*>(wg + (size_t)128 * HID);
        a0 = fma4(xv, wc[0], a0); a1 = fma4(xv, wc[1], a1);
        a2 = fma4(xv, wc[2], a2); a3 = fma4(xv, wc[3], a3);
    }
    // layer-2 partial over this lane's 16 units, then 4-lane butterfly reduce
    const float4* w2 = reinterpret_cast<const float4*>(pw2 + g * 16);
    float p = 0.0f;
    p = accdot(a0, w2[0], p); p = accdot(a1, w2[1], p);
    p = accdot(a2, w2[2], p); p = accdot(a3, w2[3], p);
    p += __shfl_xor(p, 1);
    p += __shfl_xor(p, 2);
    if (active && g == 0) {
        float act = p + pb2[0];
        unsigned m = (act > 0.0f) ? 1u : 0u;
        mask[n] = m;
        outmask[n] = m ? 1.0f : 0.0f;
        if (m) {
            unsigned slot = atomicAdd(&counters[1], 1u);
            mlist[slot] = n;
        }
    }
}

// compact edges with emask = mask[src] && !mask[tgt]; also histogram targets
__global__ void k_compact(const int* __restrict__ ei, const unsigned* __restrict__ mask,
                          unsigned* __restrict__ act_eid, unsigned* __restrict__ counters,
                          unsigned* __restrict__ hist, int E) {
    int e = blockIdx.x * blockDim.x + threadIdx.x;
    if (e >= E) return;
    int s = ei[e], t = ei[E + e];
    if (mask[s] && !mask[t]) {
        unsigned slot = atomicAdd(&counters[0], 1u);
        act_eid[slot] = (unsigned)e;
        atomicAdd(&hist[t], 1u);
    }
}

// single-block exclusive scan of hist[N] -> offs[N+1]; cursor = offs
__global__ __launch_bounds__(256) void k_scan(const unsigned* __restrict__ hist,
                                              unsigned* __restrict__ offs,
                                              unsigned* __restrict__ cursor, int N) {
    __shared__ unsigned part[256];
    unsigned t = threadIdx.x;
    unsigned chunk = ((unsigned)N + 255u) >> 8;
    unsigned lo = t * chunk, hi = lo + chunk; if (hi > (unsigned)N) hi = N;
    unsigned sum = 0;
    for (unsigned i = lo; i < hi; ++i) sum += hist[i];
    part[t] = sum;
    __syncthreads();
    // Hillis-Steele inclusive scan over 256 partials
    for (unsigned d = 1; d < 256; d <<= 1) {
        unsigned v = (t >= d) ? part[t - d] : 0u;
        __syncthreads();
        part[t] += v;
        __syncthreads();
    }
    unsigned run = part[t] - sum;                 // exclusive prefix for this thread
    for (unsigned i = lo; i < hi; ++i) {
        offs[i] = run; cursor[i] = run;
        run += hist[i];
    }
    if (t == 255) offs[N] = part[255];
}

// ---- redistribution MLP: 2 lanes per active edge, split-K, LDS weights ----
__global__ __launch_bounds__(256) void k_edge_mlp(
    const float* __restrict__ states, const int* __restrict__ ei,
    const float* __restrict__ rw1, const float* __restrict__ rb1,
    const float* __restrict__ rw2, const float* __restrict__ rb2,
    const float* __restrict__ rw3, const float* __restrict__ rb3,
    const unsigned* __restrict__ act_eid, const unsigned* __restrict__ counters,
    float* __restrict__ rawbuf, unsigned* __restrict__ segmax, int E) {
    __shared__ float wl[4096];                    // 16 KB: 32 k-rows for p=0 | 32 k-rows for p=1
    __shared__ float wl2[4096];                   // 16 KB: rw2 (row-major)
    unsigned cnt = counters[0];
    if (blockIdx.x * 128u >= cnt) return;         // whole block inactive (uniform)
    unsigned tid = threadIdx.x;
    {   // stage rw2 once (first read is after the slab-loop barriers)
        const float4* s4 = reinterpret_cast<const float4*>(rw2);
        float4* d4 = reinterpret_cast<float4*>(wl2);
        d4[tid] = s4[tid]; d4[tid + 256] = s4[tid + 256];
        d4[tid + 512] = s4[tid + 512]; d4[tid + 768] = s4[tid + 768];
    }
    unsigned grp = blockIdx.x * 128u + (tid >> 1);
    unsigned p = tid & 1u;
    bool active = grp < cnt;
    unsigned gq = active ? grp : (cnt - 1);
    int e = (int)act_eid[gq];
    int s = ei[e], tg = ei[E + e];
    const float4* myrow = reinterpret_cast<const float4*>(states + (size_t)(p ? tg : s) * D);
    float bs = (p == 0) ? 1.0f : 0.0f;
    float4 h0, h1, h2, h3, h4, h5, h6, h7, h8, h9, h10, h11, h12, h13, h14, h15;
    INIT16(rb1);
#define SCL(v) v.x *= bs; v.y *= bs; v.z *= bs; v.w *= bs;
    SCL(h0) SCL(h1) SCL(h2) SCL(h3) SCL(h4) SCL(h5) SCL(h6) SCL(h7)
    SCL(h8) SCL(h9) SCL(h10) SCL(h11) SCL(h12) SCL(h13) SCL(h14) SCL(h15)
#undef SCL
    const float4* src4 = reinterpret_cast<const float4*>(rw1);
    // prologue: prefetch slab 0 (32 k-rows of each K-half)
    float4 pf0 = src4[tid], pf1 = src4[tid + 256];
    float4 pf2 = src4[2048 + tid], pf3 = src4[2048 + tid + 256];
    for (int sl = 0; sl < 4; ++sl) {
        __syncthreads();                          // wl free
        {   // commit prefetched slab
            float4* d4 = reinterpret_cast<float4*>(wl);
            d4[tid] = pf0; d4[tid + 256] = pf1; d4[tid + 512] = pf2; d4[tid + 768] = pf3;
        }
        if (sl < 3) {                             // prefetch next slab during compute
            const float4* nx = src4 + (size_t)(sl + 1) * 512;
            pf0 = nx[tid]; pf1 = nx[tid + 256]; pf2 = nx[2048 + tid]; pf3 = nx[2048 + tid + 256];
        }
        __syncthreads();                          // slab visible
        const float4* row = myrow + sl * 8;
        const float* wb = wl + p * 2048;          // this parity's 32 k-rows
#pragma unroll 1
        for (int i = 0; i < 8; ++i) {
            float4 x = row[i];
            const float* w = wb + (size_t)(i * 4) * HID;
            ACC16(x.x, w) ACC16(x.y, w + HID) ACC16(x.z, w + 2 * HID) ACC16(x.w, w + 3 * HID)
        }
    }
    // pair-exchange partial sums -> both lanes hold full pre-activation
#define XCH1(v) { v.x += __shfl_xor(v.x, 1); v.y += __shfl_xor(v.y, 1); \
                  v.z += __shfl_xor(v.z, 1); v.w += __shfl_xor(v.w, 1); }
    XCH1(h0) XCH1(h1) XCH1(h2) XCH1(h3) XCH1(h4) XCH1(h5) XCH1(h6) XCH1(h7)
    XCH1(h8) XCH1(h9) XCH1(h10) XCH1(h11) XCH1(h12) XCH1(h13) XCH1(h14) XCH1(h15)
#undef XCH1
    SILU16();
    // layer 2: lane p computes h2 units j in [32p, 32p+32) from LDS rw2
    float4 b0, b1, b2, b3, b4, b5, b6, b7;
    { const float4* bb = reinterpret_cast<const float4*>(rb2) + p * 8;
      b0 = bb[0]; b1 = bb[1]; b2 = bb[2]; b3 = bb[3];
      b4 = bb[4]; b5 = bb[5]; b6 = bb[6]; b7 = bb[7]; }
#define L2STEP(hc, k) { const float4* _w = reinterpret_cast<const float4*>(wl2 + (size_t)(k) * HID) + p * 8; \
    b0 = fma4(hc, _w[0], b0); b1 = fma4(hc, _w[1], b1); b2 = fma4(hc, _w[2], b2); b3 = fma4(hc, _w[3], b3); \
    b4 = fma4(hc, _w[4], b4); b5 = fma4(hc, _w[5], b5); b6 = fma4(hc, _w[6], b6); b7 = fma4(hc, _w[7], b7); }
#define L2G(hr, kb) L2STEP(hr.x, kb) L2STEP(hr.y, (kb)+1) L2STEP(hr.z, (kb)+2) L2STEP(hr.w, (kb)+3)
    L2G(h0, 0)   L2G(h1, 4)   L2G(h2, 8)   L2G(h3, 12)
    L2G(h4, 16)  L2G(h5, 20)  L2G(h6, 24)  L2G(h7, 28)
    L2G(h8, 32)  L2G(h9, 36)  L2G(h10, 40) L2G(h11, 44)
    L2G(h12, 48) L2G(h13, 52) L2G(h14, 56) L2G(h15, 60)
#undef L2G
#undef L2STEP
    b0 = silu4(b0); b1 = silu4(b1); b2 = silu4(b2); b3 = silu4(b3);
    b4 = silu4(b4); b5 = silu4(b5); b6 = silu4(b6); b7 = silu4(b7);
    // layer 3: partial dot over this lane's 32 units, then pair-reduce
    const float4* w3 = reinterpret_cast<const float4*>(rw3) + p * 8;
    float part = ((dot4(b0, w3[0]) + dot4(b1, w3[1])) + (dot4(b2, w3[2]) + dot4(b3, w3[3])))
               + ((dot4(b4, w3[4]) + dot4(b5, w3[5])) + (dot4(b6, w3[6]) + dot4(b7, w3[7])));
    part += __shfl_xor(part, 1);
    if (active && p == 0) {
        float raw = part + rb3[0];
        rawbuf[grp] = raw;
        atomicMax(&segmax[s], fenc(raw));
    }
}

__global__ void k_exp(const int* __restrict__ ei, const unsigned* __restrict__ act_eid,
                      const unsigned* __restrict__ counters, const unsigned* __restrict__ segmax,
                      float* __restrict__ rawbuf, float* __restrict__ denom, int E) {
    unsigned t = blockIdx.x * blockDim.x + threadIdx.x;
    if (blockIdx.x * blockDim.x >= counters[0]) return;
    if (t >= counters[0]) return;
    int e = (int)act_eid[t];
    int s = ei[e];
    float ev = expf(rawbuf[t] - fdec(segmax[s]));
    rawbuf[t] = ev;
    atomicAdd(&denom[s], ev);
}

// bucket active slots by target: sorted[cursor[t]++] = slot
__global__ void k_fill(const int* __restrict__ ei, const unsigned* __restrict__ act_eid,
                       const unsigned* __restrict__ counters, unsigned* __restrict__ cursor,
                       unsigned* __restrict__ sorted, int E) {
    unsigned t = blockIdx.x * blockDim.x + threadIdx.x;
    if (blockIdx.x * blockDim.x >= counters[0]) return;
    if (t >= counters[0]) return;
    int e = (int)act_eid[t];
    int tg = ei[E + e];
    unsigned pos = atomicAdd(&cursor[tg], 1u);
    sorted[pos] = t;
}

// wave per node: out[n] = states[n] + sum over incoming active edges of w * states[src]
__global__ __launch_bounds__(256) void k_gather(
    const float* __restrict__ states, const int* __restrict__ ei,
    const unsigned* __restrict__ act_eid, const float* __restrict__ rawbuf,
    const float* __restrict__ denom, const unsigned* __restrict__ offs,
    const unsigned* __restrict__ sorted, float* __restrict__ out, int N, int E) {
    unsigned n = blockIdx.x * 4u + (threadIdx.x >> 6);
    unsigned lane = threadIdx.x & 63u;
    if (n >= (unsigned)N) return;
    unsigned start = offs[n], end = offs[n + 1];
    float2 acc = reinterpret_cast<const float2*>(states + (size_t)n * D)[lane];
    for (unsigned i = start; i < end; ++i) {
        unsigned slot = sorted[i];
        int e = (int)act_eid[slot];
        int s = ei[e];
        float w = rawbuf[slot] / denom[s];
        float2 sv = reinterpret_cast<const float2*>(states + (size_t)s * D)[lane];
        acc.x = fmaf(w, sv.x, acc.x);
        acc.y = fmaf(w, sv.y, acc.y);
    }
    reinterpret_cast<float2*>(out + (size_t)n * D)[lane] = acc;
}

// failed nodes: out = tanh(states @ tw + tb) * 0.05
// (failed targets receive no messages -> redistributed == states)
__global__ __launch_bounds__(256) void k_jump(
    const float* __restrict__ states,
    const float* __restrict__ tw, const float* __restrict__ tb,
    const unsigned* __restrict__ mlist, const unsigned* __restrict__ counters,
    float* __restrict__ out) {
    __shared__ float xs[8][D];
    unsigned cnt = counters[1];
    unsigned base = blockIdx.x * 8u;
    if (base >= cnt || cnt == 0) return;          // uniform
    unsigned tid = threadIdx.x;
    unsigned d = tid & 127u, r = tid >> 7;        // r in {0,1}
    {   // stage 8 rows (clamped): 32 threads per row, float4 each
        unsigned j = tid >> 5;
        unsigned c = (tid & 31u) * 4u;
        unsigned slot = base + j; if (slot >= cnt) slot = cnt - 1;
        int nn = (int)mlist[slot];
        *reinterpret_cast<float4*>(&xs[j][c]) =
            *reinterpret_cast<const float4*>(&states[(size_t)nn * D + c]);
    }
    __syncthreads();
    float tbd = tb[d];
    float a0 = tbd, a1 = tbd, a2 = tbd, a3 = tbd;
    const float* x0 = &xs[r * 4 + 0][0];
    const float* x1 = &xs[r * 4 + 1][0];
    const float* x2 = &xs[r * 4 + 2][0];
    const float* x3 = &xs[r * 4 + 3][0];
#pragma unroll 1
    for (int k = 0; k < D; ++k) {
        float w = tw[(size_t)k * D + d];
        a0 = fmaf(x0[k], w, a0);
        a1 = fmaf(x1[k], w, a1);
        a2 = fmaf(x2[k], w, a2);
        a3 = fmaf(x3[k], w, a3);
    }
    float res[4] = {a0, a1, a2, a3};
#pragma unroll
    for (int j2 = 0; j2 < 4; ++j2) {
        unsigned slot = base + r * 4 + j2;
        if (slot < cnt) {
            int nn = (int)mlist[slot];
            out[(size_t)nn * D + d] = tanhf(res[j2]) * 0.05f;
        }
    }
}

extern "C" void kernel_launch(void* const* d_in, const int* in_sizes, int n_in,
                              void* d_out, int out_size, void* d_ws, size_t ws_size,
                              hipStream_t stream) {
    const float* states = (const float*)d_in[0];
    const float* caps   = (const float*)d_in[1];
    const int*   ei     = (const int*)d_in[2];
    const float* rw1 = (const float*)d_in[3];  const float* rb1 = (const float*)d_in[4];
    const float* rw2 = (const float*)d_in[5];  const float* rb2 = (const float*)d_in[6];
    const float* rw3 = (const float*)d_in[7];  const float* rb3 = (const float*)d_in[8];
    const float* pw1 = (const float*)d_in[9];  const float* pb1 = (const float*)d_in[10];
    const float* pw2 = (const float*)d_in[11]; const float* pb2 = (const float*)d_in[12];
    const float* tw  = (const float*)d_in[13]; const float* tb  = (const float*)d_in[14];
    const int N = in_sizes[1];
    const int E = in_sizes[2] / 2;
    float* out = (float*)d_out;

    // ws layout (u32 units):
    // [0..3] counters | segmax N | denom N | hist N | mask N | mlist N |
    // offs N+1 | cursor N | act_eid E | rawbuf E | sorted E
    unsigned* ws       = (unsigned*)d_ws;
    unsigned* counters = ws;
    unsigned* segmax   = ws + 4;
    float*    denom    = (float*)(ws + 4 + 1 * (size_t)N);
    unsigned* hist     = ws + 4 + 2 * (size_t)N;
    unsigned* mask     = ws + 4 + 3 * (size_t)N;
    unsigned* mlist    = ws + 4 + 4 * (size_t)N;
    unsigned* offs     = ws + 4 + 5 * (size_t)N;
    unsigned* cursor   = ws + 4 + 6 * (size_t)N + 1;
    unsigned* act_eid  = ws + 4 + 7 * (size_t)N + 1;
    float*    rawbuf   = (float*)(act_eid + (size_t)E);
    unsigned* sorted   = act_eid + 2 * (size_t)E;

    // zero counters + segmax + denom + hist (contiguous prefix)
    (void)hipMemsetAsync(d_ws, 0, (size_t)(4 + 3 * (size_t)N) * 4, stream);

    k_protect<<<(N + 63) / 64, 256, 0, stream>>>(states, caps, pw1, pb1, pw2, pb2,
                                                 mask, mlist, counters, out + (size_t)N * D, N);
    k_compact<<<(E + 255) / 256, 256, 0, stream>>>(ei, mask, act_eid, counters, hist, E);
    k_scan<<<1, 256, 0, stream>>>(hist, offs, cursor, N);
    k_edge_mlp<<<(2 * E + 255) / 256, 256, 0, stream>>>(states, ei, rw1, rb1, rw2, rb2, rw3, rb3,
                                                        act_eid, counters, rawbuf, segmax, E);
    k_exp<<<(E + 255) / 256, 256, 0, stream>>>(ei, act_eid, counters, segmax, rawbuf, denom, E);
    k_fill<<<(E + 255) / 256, 256, 0, stream>>>(ei, act_eid, counters, cursor, sorted, E);
    k_gather<<<(N + 3) / 4, 256, 0, stream>>>(states, ei, act_eid, rawbuf, denom,
                                              offs, sorted, out, N, E);
    k_jump<<<(N + 7) / 8, 256, 0, stream>>>(states, tw, tb, mlist, counters, out);
}

// Round 10
// 428.417 us; speedup vs baseline: 1.3508x; 1.3508x over previous
//
#include <hip/hip_runtime.h>
#include <cmath>

#define D 128
#define HID 64

__device__ __forceinline__ float silu_f(float x) { return x / (1.0f + expf(-x)); }

__device__ __forceinline__ float4 fma4(float a, float4 w, float4 c) {
    c.x = fmaf(a, w.x, c.x); c.y = fmaf(a, w.y, c.y);
    c.z = fmaf(a, w.z, c.z); c.w = fmaf(a, w.w, c.w);
    return c;
}
__device__ __forceinline__ float4 silu4(float4 v) {
    v.x = silu_f(v.x); v.y = silu_f(v.y); v.z = silu_f(v.z); v.w = silu_f(v.w);
    return v;
}

// order-preserving float <-> uint encode for atomicMax on floats
__device__ __forceinline__ unsigned fenc(float f) {
    unsigned u = __float_as_uint(f);
    return (u & 0x80000000u) ? ~u : (u | 0x80000000u);
}
__device__ __forceinline__ float fdec(unsigned e) {
    unsigned u = (e & 0x80000000u) ? (e & 0x7FFFFFFFu) : ~e;
    return __uint_as_float(u);
}

#define ACC16(xv, wp) { const float4* _w4 = reinterpret_cast<const float4*>(wp); \
    h0  = fma4(xv, _w4[0],  h0);  h1  = fma4(xv, _w4[1],  h1);  \
    h2  = fma4(xv, _w4[2],  h2);  h3  = fma4(xv, _w4[3],  h3);  \
    h4  = fma4(xv, _w4[4],  h4);  h5  = fma4(xv, _w4[5],  h5);  \
    h6  = fma4(xv, _w4[6],  h6);  h7  = fma4(xv, _w4[7],  h7);  \
    h8  = fma4(xv, _w4[8],  h8);  h9  = fma4(xv, _w4[9],  h9);  \
    h10 = fma4(xv, _w4[10], h10); h11 = fma4(xv, _w4[11], h11); \
    h12 = fma4(xv, _w4[12], h12); h13 = fma4(xv, _w4[13], h13); \
    h14 = fma4(xv, _w4[14], h14); h15 = fma4(xv, _w4[15], h15); }

#define INIT16(bp) { const float4* _b4 = reinterpret_cast<const float4*>(bp); \
    h0 = _b4[0]; h1 = _b4[1]; h2 = _b4[2]; h3 = _b4[3]; \
    h4 = _b4[4]; h5 = _b4[5]; h6 = _b4[6]; h7 = _b4[7]; \
    h8 = _b4[8]; h9 = _b4[9]; h10 = _b4[10]; h11 = _b4[11]; \
    h12 = _b4[12]; h13 = _b4[13]; h14 = _b4[14]; h15 = _b4[15]; }

#define SILU16() { h0 = silu4(h0); h1 = silu4(h1); h2 = silu4(h2); h3 = silu4(h3); \
    h4 = silu4(h4); h5 = silu4(h5); h6 = silu4(h6); h7 = silu4(h7); \
    h8 = silu4(h8); h9 = silu4(h9); h10 = silu4(h10); h11 = silu4(h11); \
    h12 = silu4(h12); h13 = silu4(h13); h14 = silu4(h14); h15 = silu4(h15); }

// dot with 4 partial sums, k%4 -> s0..s3 (matches r1/r2 ordering)
__device__ __forceinline__ void fd4(float4 h, float4 w, float& s0, float& s1, float& s2, float& s3) {
    s0 = fmaf(h.x, w.x, s0); s1 = fmaf(h.y, w.y, s1);
    s2 = fmaf(h.z, w.z, s2); s3 = fmaf(h.w, w.w, s3);
}
#define FD16(w4) { fd4(h0, w4[0], s0, s1, s2, s3);  fd4(h1, w4[1], s0, s1, s2, s3);  \
    fd4(h2, w4[2], s0, s1, s2, s3);  fd4(h3, w4[3], s0, s1, s2, s3);  \
    fd4(h4, w4[4], s0, s1, s2, s3);  fd4(h5, w4[5], s0, s1, s2, s3);  \
    fd4(h6, w4[6], s0, s1, s2, s3);  fd4(h7, w4[7], s0, s1, s2, s3);  \
    fd4(h8, w4[8], s0, s1, s2, s3);  fd4(h9, w4[9], s0, s1, s2, s3);  \
    fd4(h10, w4[10], s0, s1, s2, s3); fd4(h11, w4[11], s0, s1, s2, s3); \
    fd4(h12, w4[12], s0, s1, s2, s3); fd4(h13, w4[13], s0, s1, s2, s3); \
    fd4(h14, w4[14], s0, s1, s2, s3); fd4(h15, w4[15], s0, s1, s2, s3); }

// serial silu-dot over 4 units
__device__ __forceinline__ float accdot(float4 h, float4 w, float act) {
    act = fmaf(silu_f(h.x), w.x, act);
    act = fmaf(silu_f(h.y), w.y, act);
    act = fmaf(silu_f(h.z), w.z, act);
    act = fmaf(silu_f(h.w), w.w, act);
    return act;
}

// ---- protection net: 4 lanes/node split-hid, full pw1 in LDS, 64 nodes/block ----
__global__ __launch_bounds__(256) void k_protect(
    const float* __restrict__ states, const float* __restrict__ caps,
    const float* __restrict__ pw1, const float* __restrict__ pb1,
    const float* __restrict__ pw2, const float* __restrict__ pb2,
    unsigned* __restrict__ mask, unsigned* __restrict__ mlist,
    unsigned* __restrict__ counters, float* __restrict__ outmask, int N) {
    __shared__ float wl[129 * 64];                // 33 KB: all of pw1 (incl. capacity row)
    unsigned tid = threadIdx.x;
    {   // stage 8256 floats = 2064 float4, coalesced
        const float4* s4 = reinterpret_cast<const float4*>(pw1);
        float4* d4 = reinterpret_cast<float4*>(wl);
#pragma unroll
        for (int q = 0; q < 9; ++q) {
            unsigned idx = tid + q * 256u;
            if (idx < 2064u) d4[idx] = s4[idx];
        }
    }
    __syncthreads();
    unsigned nl = tid >> 2, g = tid & 3u;         // lane g owns hidden units [g*16, g*16+16)
    unsigned n = blockIdx.x * 64u + nl;
    bool active = n < (unsigned)N;
    unsigned nq = active ? n : (unsigned)(N - 1);
    const float4* row = reinterpret_cast<const float4*>(states + (size_t)nq * D);
    float4 a0, a1, a2, a3;
    { const float4* b4 = reinterpret_cast<const float4*>(pb1 + g * 16);
      a0 = b4[0]; a1 = b4[1]; a2 = b4[2]; a3 = b4[3]; }
    const float* wg = wl + g * 16;
#pragma unroll 1
    for (int kb = 0; kb < 32; ++kb) {
        float4 x = row[kb];
        const float* w = wg + (size_t)kb * 4 * HID;
        const float4* w0 = reinterpret_cast<const float4*>(w);
        const float4* w1 = reinterpret_cast<const float4*>(w + HID);
        const float4* w2q = reinterpret_cast<const float4*>(w + 2 * HID);
        const float4* w3q = reinterpret_cast<const float4*>(w + 3 * HID);
        a0 = fma4(x.x, w0[0], a0); a1 = fma4(x.x, w0[1], a1); a2 = fma4(x.x, w0[2], a2); a3 = fma4(x.x, w0[3], a3);
        a0 = fma4(x.y, w1[0], a0); a1 = fma4(x.y, w1[1], a1); a2 = fma4(x.y, w1[2], a2); a3 = fma4(x.y, w1[3], a3);
        a0 = fma4(x.z, w2q[0], a0); a1 = fma4(x.z, w2q[1], a1); a2 = fma4(x.z, w2q[2], a2); a3 = fma4(x.z, w2q[3], a3);
        a0 = fma4(x.w, w3q[0], a0); a1 = fma4(x.w, w3q[1], a1); a2 = fma4(x.w, w3q[2], a2); a3 = fma4(x.w, w3q[3], a3);
    }
    {   // capacity row (input dim 128)
        float xv = caps[nq];
        const float4* wc = reinterpret_cast<const float4*>(wg + (size_t)128 * HID);
        a0 = fma4(xv, wc[0], a0); a1 = fma4(xv, wc[1], a1);
        a2 = fma4(xv, wc[2], a2); a3 = fma4(xv, wc[3], a3);
    }
    // layer-2 partial over this lane's 16 units, then 4-lane butterfly reduce
    const float4* w2 = reinterpret_cast<const float4*>(pw2 + g * 16);
    float p = 0.0f;
    p = accdot(a0, w2[0], p); p = accdot(a1, w2[1], p);
    p = accdot(a2, w2[2], p); p = accdot(a3, w2[3], p);
    p += __shfl_xor(p, 1);
    p += __shfl_xor(p, 2);
    if (active && g == 0) {
        float act = p + pb2[0];
        unsigned m = (act > 0.0f) ? 1u : 0u;
        mask[n] = m;
        outmask[n] = m ? 1.0f : 0.0f;
        if (m) {
            unsigned slot = atomicAdd(&counters[1], 1u);
            mlist[slot] = n;
        }
    }
}

// compact edges with emask = mask[src] && !mask[tgt]; also histogram targets
__global__ void k_compact(const int* __restrict__ ei, const unsigned* __restrict__ mask,
                          unsigned* __restrict__ act_eid, unsigned* __restrict__ counters,
                          unsigned* __restrict__ hist, int E) {
    int e = blockIdx.x * blockDim.x + threadIdx.x;
    if (e >= E) return;
    int s = ei[e], t = ei[E + e];
    if (mask[s] && !mask[t]) {
        unsigned slot = atomicAdd(&counters[0], 1u);
        act_eid[slot] = (unsigned)e;
        atomicAdd(&hist[t], 1u);
    }
}

// --- hierarchical exclusive scan of hist[N] -> offs[N+1], cursor[N] ---
// A: per-block (256-wide) sums
__global__ __launch_bounds__(256) void k_scanA(const unsigned* __restrict__ hist,
                                               unsigned* __restrict__ bsum, int N) {
    __shared__ unsigned sm[256];
    unsigned t = threadIdx.x;
    unsigned i = blockIdx.x * 256u + t;
    sm[t] = (i < (unsigned)N) ? hist[i] : 0u;
    __syncthreads();
#pragma unroll
    for (unsigned d = 128; d > 0; d >>= 1) {
        if (t < d) sm[t] += sm[t + d];
        __syncthreads();
    }
    if (t == 0) bsum[blockIdx.x] = sm[0];
}
// B: scan of block sums (nb <= 256)
__global__ __launch_bounds__(256) void k_scanB(const unsigned* __restrict__ bsum,
                                               unsigned* __restrict__ bpre, int nb) {
    __shared__ unsigned sm[256];
    unsigned t = threadIdx.x;
    unsigned v = (t < (unsigned)nb) ? bsum[t] : 0u;
    sm[t] = v;
    __syncthreads();
    for (unsigned d = 1; d < 256; d <<= 1) {
        unsigned x = (t >= d) ? sm[t - d] : 0u;
        __syncthreads();
        sm[t] += x;
        __syncthreads();
    }
    if (t < (unsigned)nb) bpre[t] = sm[t] - v;    // exclusive
}
// C: local inclusive scan + block prefix -> offs/cursor
__global__ __launch_bounds__(256) void k_scanC(const unsigned* __restrict__ hist,
                                               const unsigned* __restrict__ bpre,
                                               unsigned* __restrict__ offs,
                                               unsigned* __restrict__ cursor, int N) {
    __shared__ unsigned sm[256];
    unsigned t = threadIdx.x;
    unsigned i = blockIdx.x * 256u + t;
    unsigned v = (i < (unsigned)N) ? hist[i] : 0u;
    sm[t] = v;
    __syncthreads();
    for (unsigned d = 1; d < 256; d <<= 1) {
        unsigned x = (t >= d) ? sm[t - d] : 0u;
        __syncthreads();
        sm[t] += x;
        __syncthreads();
    }
    unsigned exc = sm[t] - v + bpre[blockIdx.x];
    if (i < (unsigned)N) { offs[i] = exc; cursor[i] = exc; }
    if (i == (unsigned)N - 1) offs[N] = exc + v;
}

// ---- redistribution MLP: 1 lane/edge, LDS-staged weights (r7 structure) ----
__global__ __launch_bounds__(256) void k_edge_mlp(
    const float* __restrict__ states, const int* __restrict__ ei,
    const float* __restrict__ rw1, const float* __restrict__ rb1,
    const float* __restrict__ rw2, const float* __restrict__ rb2,
    const float* __restrict__ rw3, const float* __restrict__ rb3,
    const unsigned* __restrict__ act_eid, const unsigned* __restrict__ counters,
    float* __restrict__ rawbuf, unsigned* __restrict__ segmax, int E) {
    __shared__ float wl[4096];                    // 16 KB slab (64 K-rows of rw1)
    __shared__ float w2t[64 * 68];                // rw2 transposed, padded stride
    unsigned cnt = counters[0];
    if (blockIdx.x * 256u >= cnt) return;         // whole block inactive (uniform)
    unsigned tid = threadIdx.x;
    // stage rw2 transposed once (read after the slab loop; barriers order it)
#pragma unroll
    for (int q = 0; q < 16; ++q) {
        int i = (int)tid + q * 256;
        w2t[(i & 63) * 68 + (i >> 6)] = rw2[i];
    }
    unsigned grp = blockIdx.x * 256u + tid;
    bool active = grp < cnt;
    unsigned gq = active ? grp : (cnt - 1);
    int e = (int)act_eid[gq];
    int s = ei[e], tg = ei[E + e];
    const float4* rowA = reinterpret_cast<const float4*>(states + (size_t)s * D);
    const float4* rowB = reinterpret_cast<const float4*>(states + (size_t)tg * D);
    float4 h0, h1, h2, h3, h4, h5, h6, h7, h8, h9, h10, h11, h12, h13, h14, h15;
    INIT16(rb1);
    const float4* src4 = reinterpret_cast<const float4*>(rw1);
    // prologue: prefetch slab 0 into registers
    float4 pf0 = src4[tid], pf1 = src4[tid + 256], pf2 = src4[tid + 512], pf3 = src4[tid + 768];
    for (int sl = 0; sl < 4; ++sl) {
        __syncthreads();                          // wl free (prev compute done)
        {   // commit prefetched slab to LDS
            float4* d4 = reinterpret_cast<float4*>(wl);
            d4[tid] = pf0; d4[tid + 256] = pf1; d4[tid + 512] = pf2; d4[tid + 768] = pf3;
        }
        if (sl < 3) {                             // issue next-slab loads; land during compute
            const float4* nx = src4 + (size_t)(sl + 1) * 1024;
            pf0 = nx[tid]; pf1 = nx[tid + 256]; pf2 = nx[tid + 512]; pf3 = nx[tid + 768];
        }
        __syncthreads();                          // slab visible
        const float4* row = (sl < 2) ? (rowA + sl * 16) : (rowB + (sl - 2) * 16);
#pragma unroll 1
        for (int i = 0; i < 16; ++i) {
            float4 x = row[i];
            const float* w = wl + (size_t)(i * 4) * HID;
            ACC16(x.x, w) ACC16(x.y, w + HID) ACC16(x.z, w + 2 * HID) ACC16(x.w, w + 3 * HID)
        }
    }
    SILU16();
    // layers 2+3 fused: per j, dot(h, rw2T[j]) -> silu -> raw += h2*rw3[j]
    float raw = rb3[0];
#pragma unroll 1
    for (int j = 0; j < HID; ++j) {
        const float4* w4 = reinterpret_cast<const float4*>(w2t + j * 68);
        float s0 = rb2[j], s1 = 0.f, s2 = 0.f, s3 = 0.f;
        FD16(w4);
        float h2v = silu_f((s0 + s1) + (s2 + s3));
        raw = fmaf(h2v, rw3[j], raw);
    }
    if (active) {
        rawbuf[grp] = raw;
        atomicMax(&segmax[s], fenc(raw));
    }
}

__global__ void k_exp(const int* __restrict__ ei, const unsigned* __restrict__ act_eid,
                      const unsigned* __restrict__ counters, const unsigned* __restrict__ segmax,
                      float* __restrict__ rawbuf, float* __restrict__ denom, int E) {
    unsigned t = blockIdx.x * blockDim.x + threadIdx.x;
    if (blockIdx.x * blockDim.x >= counters[0]) return;
    if (t >= counters[0]) return;
    int e = (int)act_eid[t];
    int s = ei[e];
    float ev = expf(rawbuf[t] - fdec(segmax[s]));
    rawbuf[t] = ev;
    atomicAdd(&denom[s], ev);
}

// bucket by target with final weight + src pre-packed (coalesced streams for gather)
__global__ void k_fill(const int* __restrict__ ei, const unsigned* __restrict__ act_eid,
                       const unsigned* __restrict__ counters, const float* __restrict__ rawbuf,
                       const float* __restrict__ denom, unsigned* __restrict__ cursor,
                       float* __restrict__ wbuf, unsigned* __restrict__ sbuf, int E) {
    unsigned t = blockIdx.x * blockDim.x + threadIdx.x;
    if (blockIdx.x * blockDim.x >= counters[0]) return;
    if (t >= counters[0]) return;
    int e = (int)act_eid[t];
    int s = ei[e], tg = ei[E + e];
    float w = rawbuf[t] / denom[s];
    unsigned pos = atomicAdd(&cursor[tg], 1u);
    wbuf[pos] = w;
    sbuf[pos] = (unsigned)s;
}

// wave per node: out[n] = states[n] + sum_{incoming active} w * states[src]
__global__ __launch_bounds__(256) void k_gather(
    const float* __restrict__ states, const float* __restrict__ wbuf,
    const unsigned* __restrict__ sbuf, const unsigned* __restrict__ offs,
    float* __restrict__ out, int N) {
    unsigned n = blockIdx.x * 4u + (threadIdx.x >> 6);
    unsigned lane = threadIdx.x & 63u;
    if (n >= (unsigned)N) return;
    unsigned start = offs[n], end = offs[n + 1];
    float2 acc = reinterpret_cast<const float2*>(states + (size_t)n * D)[lane];
    for (unsigned i = start; i < end; ++i) {
        float w = wbuf[i];
        unsigned s = sbuf[i];
        float2 sv = reinterpret_cast<const float2*>(states + (size_t)s * D)[lane];
        acc.x = fmaf(w, sv.x, acc.x);
        acc.y = fmaf(w, sv.y, acc.y);
    }
    reinterpret_cast<float2*>(out + (size_t)n * D)[lane] = acc;
}

// failed nodes: out = tanh(states @ tw + tb) * 0.05
// (failed targets receive no messages -> redistributed == states)
__global__ __launch_bounds__(256) void k_jump(
    const float* __restrict__ states,
    const float* __restrict__ tw, const float* __restrict__ tb,
    const unsigned* __restrict__ mlist, const unsigned* __restrict__ counters,
    float* __restrict__ out) {
    __shared__ float xs[8][D];
    unsigned cnt = counters[1];
    unsigned base = blockIdx.x * 8u;
    if (base >= cnt || cnt == 0) return;          // uniform
    unsigned tid = threadIdx.x;
    unsigned d = tid & 127u, r = tid >> 7;        // r in {0,1}
    {   // stage 8 rows (clamped): 32 threads per row, float4 each
        unsigned j = tid >> 5;
        unsigned c = (tid & 31u) * 4u;
        unsigned slot = base + j; if (slot >= cnt) slot = cnt - 1;
        int nn = (int)mlist[slot];
        *reinterpret_cast<float4*>(&xs[j][c]) =
            *reinterpret_cast<const float4*>(&states[(size_t)nn * D + c]);
    }
    __syncthreads();
    float tbd = tb[d];
    float a0 = tbd, a1 = tbd, a2 = tbd, a3 = tbd;
    const float* x0 = &xs[r * 4 + 0][0];
    const float* x1 = &xs[r * 4 + 1][0];
    const float* x2 = &xs[r * 4 + 2][0];
    const float* x3 = &xs[r * 4 + 3][0];
#pragma unroll 1
    for (int k = 0; k < D; ++k) {
        float w = tw[(size_t)k * D + d];
        a0 = fmaf(x0[k], w, a0);
        a1 = fmaf(x1[k], w, a1);
        a2 = fmaf(x2[k], w, a2);
        a3 = fmaf(x3[k], w, a3);
    }
    float res[4] = {a0, a1, a2, a3};
#pragma unroll
    for (int j2 = 0; j2 < 4; ++j2) {
        unsigned slot = base + r * 4 + j2;
        if (slot < cnt) {
            int nn = (int)mlist[slot];
            out[(size_t)nn * D + d] = tanhf(res[j2]) * 0.05f;
        }
    }
}

extern "C" void kernel_launch(void* const* d_in, const int* in_sizes, int n_in,
                              void* d_out, int out_size, void* d_ws, size_t ws_size,
                              hipStream_t stream) {
    const float* states = (const float*)d_in[0];
    const float* caps   = (const float*)d_in[1];
    const int*   ei     = (const int*)d_in[2];
    const float* rw1 = (const float*)d_in[3];  const float* rb1 = (const float*)d_in[4];
    const float* rw2 = (const float*)d_in[5];  const float* rb2 = (const float*)d_in[6];
    const float* rw3 = (const float*)d_in[7];  const float* rb3 = (const float*)d_in[8];
    const float* pw1 = (const float*)d_in[9];  const float* pb1 = (const float*)d_in[10];
    const float* pw2 = (const float*)d_in[11]; const float* pb2 = (const float*)d_in[12];
    const float* tw  = (const float*)d_in[13]; const float* tb  = (const float*)d_in[14];
    const int N = in_sizes[1];
    const int E = in_sizes[2] / 2;
    float* out = (float*)d_out;
    const int nb = (N + 255) / 256;

    // ws layout (u32 units):
    // [0..3] counters | segmax N | denom N | hist N | mask N | mlist N |
    // offs N+1 | cursor N | bsum 256 | bpre 256 | act_eid E | rawbuf E | wbuf E | sbuf E
    unsigned* ws       = (unsigned*)d_ws;
    unsigned* counters = ws;
    unsigned* segmax   = ws + 4;
    float*    denom    = (float*)(ws + 4 + 1 * (size_t)N);
    unsigned* hist     = ws + 4 + 2 * (size_t)N;
    unsigned* mask     = ws + 4 + 3 * (size_t)N;
    unsigned* mlist    = ws + 4 + 4 * (size_t)N;
    unsigned* offs     = ws + 4 + 5 * (size_t)N;
    unsigned* cursor   = ws + 4 + 6 * (size_t)N + 1;
    unsigned* bsum     = ws + 4 + 7 * (size_t)N + 1;
    unsigned* bpre     = bsum + 256;
    unsigned* act_eid  = bpre + 256;
    float*    rawbuf   = (float*)(act_eid + (size_t)E);
    float*    wbuf     = (float*)(act_eid + 2 * (size_t)E);
    unsigned* sbuf     = act_eid + 3 * (size_t)E;

    // zero counters + segmax + denom + hist (contiguous prefix)
    (void)hipMemsetAsync(d_ws, 0, (size_t)(4 + 3 * (size_t)N) * 4, stream);

    k_protect<<<(N + 63) / 64, 256, 0, stream>>>(states, caps, pw1, pb1, pw2, pb2,
                                                 mask, mlist, counters, out + (size_t)N * D, N);
    k_compact<<<(E + 255) / 256, 256, 0, stream>>>(ei, mask, act_eid, counters, hist, E);
    k_scanA<<<nb, 256, 0, stream>>>(hist, bsum, N);
    k_scanB<<<1, 256, 0, stream>>>(bsum, bpre, nb);
    k_scanC<<<nb, 256, 0, stream>>>(hist, bpre, offs, cursor, N);
    k_edge_mlp<<<(E + 255) / 256, 256, 0, stream>>>(states, ei, rw1, rb1, rw2, rb2, rw3, rb3,
                                                    act_eid, counters, rawbuf, segmax, E);
    k_exp<<<(E + 255) / 256, 256, 0, stream>>>(ei, act_eid, counters, segmax, rawbuf, denom, E);
    k_fill<<<(E + 255) / 256, 256, 0, stream>>>(ei, act_eid, counters, rawbuf, denom,
                                                cursor, wbuf, sbuf, E);
    k_gather<<<(N + 3) / 4, 256, 0, stream>>>(states, wbuf, sbuf, offs, out, N);
    k_jump<<<(N + 7) / 8, 256, 0, stream>>>(states, tw, tb, mlist, counters, out);
}

// Round 11
// 373.941 us; speedup vs baseline: 1.5476x; 1.1457x over previous
//
#include <hip/hip_runtime.h>
#include <cmath>

#define D 128
#define HID 64

__device__ __forceinline__ float silu_f(float x) { return x / (1.0f + expf(-x)); }

__device__ __forceinline__ float4 fma4(float a, float4 w, float4 c) {
    c.x = fmaf(a, w.x, c.x); c.y = fmaf(a, w.y, c.y);
    c.z = fmaf(a, w.z, c.z); c.w = fmaf(a, w.w, c.w);
    return c;
}
__device__ __forceinline__ float4 silu4(float4 v) {
    v.x = silu_f(v.x); v.y = silu_f(v.y); v.z = silu_f(v.z); v.w = silu_f(v.w);
    return v;
}

// order-preserving float <-> uint encode for atomicMax on floats
__device__ __forceinline__ unsigned fenc(float f) {
    unsigned u = __float_as_uint(f);
    return (u & 0x80000000u) ? ~u : (u | 0x80000000u);
}
__device__ __forceinline__ float fdec(unsigned e) {
    unsigned u = (e & 0x80000000u) ? (e & 0x7FFFFFFFu) : ~e;
    return __uint_as_float(u);
}

#define INIT16(bp) { const float4* _b4 = reinterpret_cast<const float4*>(bp); \
    h0 = _b4[0]; h1 = _b4[1]; h2 = _b4[2]; h3 = _b4[3]; \
    h4 = _b4[4]; h5 = _b4[5]; h6 = _b4[6]; h7 = _b4[7]; \
    h8 = _b4[8]; h9 = _b4[9]; h10 = _b4[10]; h11 = _b4[11]; \
    h12 = _b4[12]; h13 = _b4[13]; h14 = _b4[14]; h15 = _b4[15]; }

#define SILU16() { h0 = silu4(h0); h1 = silu4(h1); h2 = silu4(h2); h3 = silu4(h3); \
    h4 = silu4(h4); h5 = silu4(h5); h6 = silu4(h6); h7 = silu4(h7); \
    h8 = silu4(h8); h9 = silu4(h9); h10 = silu4(h10); h11 = silu4(h11); \
    h12 = silu4(h12); h13 = silu4(h13); h14 = silu4(h14); h15 = silu4(h15); }

// dot with 4 partial sums, k%4 -> s0..s3 (matches r1/r2 ordering)
__device__ __forceinline__ void fd4(float4 h, float4 w, float& s0, float& s1, float& s2, float& s3) {
    s0 = fmaf(h.x, w.x, s0); s1 = fmaf(h.y, w.y, s1);
    s2 = fmaf(h.z, w.z, s2); s3 = fmaf(h.w, w.w, s3);
}
#define FD16(w4) { fd4(h0, w4[0], s0, s1, s2, s3);  fd4(h1, w4[1], s0, s1, s2, s3);  \
    fd4(h2, w4[2], s0, s1, s2, s3);  fd4(h3, w4[3], s0, s1, s2, s3);  \
    fd4(h4, w4[4], s0, s1, s2, s3);  fd4(h5, w4[5], s0, s1, s2, s3);  \
    fd4(h6, w4[6], s0, s1, s2, s3);  fd4(h7, w4[7], s0, s1, s2, s3);  \
    fd4(h8, w4[8], s0, s1, s2, s3);  fd4(h9, w4[9], s0, s1, s2, s3);  \
    fd4(h10, w4[10], s0, s1, s2, s3); fd4(h11, w4[11], s0, s1, s2, s3); \
    fd4(h12, w4[12], s0, s1, s2, s3); fd4(h13, w4[13], s0, s1, s2, s3); \
    fd4(h14, w4[14], s0, s1, s2, s3); fd4(h15, w4[15], s0, s1, s2, s3); }

// serial silu-dot over 4 units
__device__ __forceinline__ float accdot(float4 h, float4 w, float act) {
    act = fmaf(silu_f(h.x), w.x, act);
    act = fmaf(silu_f(h.y), w.y, act);
    act = fmaf(silu_f(h.z), w.z, act);
    act = fmaf(silu_f(h.w), w.w, act);
    return act;
}

// ---- protection net: 4 lanes/node split-hid, full pw1 in LDS, 64 nodes/block ----
__global__ __launch_bounds__(256) void k_protect(
    const float* __restrict__ states, const float* __restrict__ caps,
    const float* __restrict__ pw1, const float* __restrict__ pb1,
    const float* __restrict__ pw2, const float* __restrict__ pb2,
    unsigned* __restrict__ mask, unsigned* __restrict__ mlist,
    unsigned* __restrict__ counters, float* __restrict__ outmask, int N) {
    __shared__ float wl[129 * 64];                // 33 KB: all of pw1 (incl. capacity row)
    unsigned tid = threadIdx.x;
    {   // stage 8256 floats = 2064 float4, coalesced
        const float4* s4 = reinterpret_cast<const float4*>(pw1);
        float4* d4 = reinterpret_cast<float4*>(wl);
#pragma unroll
        for (int q = 0; q < 9; ++q) {
            unsigned idx = tid + q * 256u;
            if (idx < 2064u) d4[idx] = s4[idx];
        }
    }
    __syncthreads();
    unsigned nl = tid >> 2, g = tid & 3u;         // lane g owns hidden units [g*16, g*16+16)
    unsigned n = blockIdx.x * 64u + nl;
    bool active = n < (unsigned)N;
    unsigned nq = active ? n : (unsigned)(N - 1);
    const float4* row = reinterpret_cast<const float4*>(states + (size_t)nq * D);
    float4 a0, a1, a2, a3;
    { const float4* b4 = reinterpret_cast<const float4*>(pb1 + g * 16);
      a0 = b4[0]; a1 = b4[1]; a2 = b4[2]; a3 = b4[3]; }
    const float* wg = wl + g * 16;
#pragma unroll 1
    for (int kb = 0; kb < 32; ++kb) {
        float4 x = row[kb];
        const float* w = wg + (size_t)kb * 4 * HID;
        const float4* w0 = reinterpret_cast<const float4*>(w);
        const float4* w1 = reinterpret_cast<const float4*>(w + HID);
        const float4* w2q = reinterpret_cast<const float4*>(w + 2 * HID);
        const float4* w3q = reinterpret_cast<const float4*>(w + 3 * HID);
        a0 = fma4(x.x, w0[0], a0); a1 = fma4(x.x, w0[1], a1); a2 = fma4(x.x, w0[2], a2); a3 = fma4(x.x, w0[3], a3);
        a0 = fma4(x.y, w1[0], a0); a1 = fma4(x.y, w1[1], a1); a2 = fma4(x.y, w1[2], a2); a3 = fma4(x.y, w1[3], a3);
        a0 = fma4(x.z, w2q[0], a0); a1 = fma4(x.z, w2q[1], a1); a2 = fma4(x.z, w2q[2], a2); a3 = fma4(x.z, w2q[3], a3);
        a0 = fma4(x.w, w3q[0], a0); a1 = fma4(x.w, w3q[1], a1); a2 = fma4(x.w, w3q[2], a2); a3 = fma4(x.w, w3q[3], a3);
    }
    {   // capacity row (input dim 128)
        float xv = caps[nq];
        const float4* wc = reinterpret_cast<const float4*>(wg + (size_t)128 * HID);
        a0 = fma4(xv, wc[0], a0); a1 = fma4(xv, wc[1], a1);
        a2 = fma4(xv, wc[2], a2); a3 = fma4(xv, wc[3], a3);
    }
    // layer-2 partial over this lane's 16 units, then 4-lane butterfly reduce
    const float4* w2 = reinterpret_cast<const float4*>(pw2 + g * 16);
    float p = 0.0f;
    p = accdot(a0, w2[0], p); p = accdot(a1, w2[1], p);
    p = accdot(a2, w2[2], p); p = accdot(a3, w2[3], p);
    p += __shfl_xor(p, 1);
    p += __shfl_xor(p, 2);
    if (active && g == 0) {
        float act = p + pb2[0];
        unsigned m = (act > 0.0f) ? 1u : 0u;
        mask[n] = m;
        outmask[n] = m ? 1.0f : 0.0f;
        if (m) {
            unsigned slot = atomicAdd(&counters[1], 1u);
            mlist[slot] = n;
        }
    }
}

// ---- per-node layer-1 factorization: uv[n] = (mask ? W1a : W1b) @ states[n] ----
// failed nodes are only ever message SOURCES (rows 0..127 of rw1);
// alive nodes are only ever message TARGETS (rows 128..255).
__global__ __launch_bounds__(256) void k_nodemlp(
    const float* __restrict__ states, const unsigned* __restrict__ mask,
    const float* __restrict__ rw1, float* __restrict__ uv, int N) {
    __shared__ float wl[16384];                   // 64 KB: W1a (8192) | W1b (8192)
    unsigned tid = threadIdx.x;
    {   // stage all of rw1: 4096 float4, coalesced
        const float4* s4 = reinterpret_cast<const float4*>(rw1);
        float4* d4 = reinterpret_cast<float4*>(wl);
#pragma unroll
        for (int q = 0; q < 16; ++q) d4[tid + q * 256u] = s4[tid + q * 256u];
    }
    __syncthreads();
    unsigned nl = tid >> 2, g = tid & 3u;
    unsigned n = blockIdx.x * 64u + nl;
    if (n >= (unsigned)N) return;
    const float4* row = reinterpret_cast<const float4*>(states + (size_t)n * D);
    unsigned m = mask[n];
    const float* wg = wl + (m ? 0u : 8192u) + g * 16;
    float4 a0, a1, a2, a3;
    a0.x=a0.y=a0.z=a0.w=0.f; a1=a0; a2=a0; a3=a0;
#pragma unroll 1
    for (int kb = 0; kb < 32; ++kb) {
        float4 x = row[kb];
        const float* w = wg + (size_t)kb * 4 * HID;
        const float4* w0 = reinterpret_cast<const float4*>(w);
        const float4* w1 = reinterpret_cast<const float4*>(w + HID);
        const float4* w2q = reinterpret_cast<const float4*>(w + 2 * HID);
        const float4* w3q = reinterpret_cast<const float4*>(w + 3 * HID);
        a0 = fma4(x.x, w0[0], a0); a1 = fma4(x.x, w0[1], a1); a2 = fma4(x.x, w0[2], a2); a3 = fma4(x.x, w0[3], a3);
        a0 = fma4(x.y, w1[0], a0); a1 = fma4(x.y, w1[1], a1); a2 = fma4(x.y, w1[2], a2); a3 = fma4(x.y, w1[3], a3);
        a0 = fma4(x.z, w2q[0], a0); a1 = fma4(x.z, w2q[1], a1); a2 = fma4(x.z, w2q[2], a2); a3 = fma4(x.z, w2q[3], a3);
        a0 = fma4(x.w, w3q[0], a0); a1 = fma4(x.w, w3q[1], a1); a2 = fma4(x.w, w3q[2], a2); a3 = fma4(x.w, w3q[3], a3);
    }
    float4* o = reinterpret_cast<float4*>(uv + (size_t)n * HID + g * 16);
    o[0] = a0; o[1] = a1; o[2] = a2; o[3] = a3;
}

// compact edges with emask = mask[src] && !mask[tgt]; also histogram targets
__global__ void k_compact(const int* __restrict__ ei, const unsigned* __restrict__ mask,
                          unsigned* __restrict__ act_eid, unsigned* __restrict__ counters,
                          unsigned* __restrict__ hist, int E) {
    int e = blockIdx.x * blockDim.x + threadIdx.x;
    if (e >= E) return;
    int s = ei[e], t = ei[E + e];
    if (mask[s] && !mask[t]) {
        unsigned slot = atomicAdd(&counters[0], 1u);
        act_eid[slot] = (unsigned)e;
        atomicAdd(&hist[t], 1u);
    }
}

// --- hierarchical exclusive scan of hist[N] -> offs[N+1], cursor[N] ---
__global__ __launch_bounds__(256) void k_scanA(const unsigned* __restrict__ hist,
                                               unsigned* __restrict__ bsum, int N) {
    __shared__ unsigned sm[256];
    unsigned t = threadIdx.x;
    unsigned i = blockIdx.x * 256u + t;
    sm[t] = (i < (unsigned)N) ? hist[i] : 0u;
    __syncthreads();
#pragma unroll
    for (unsigned d = 128; d > 0; d >>= 1) {
        if (t < d) sm[t] += sm[t + d];
        __syncthreads();
    }
    if (t == 0) bsum[blockIdx.x] = sm[0];
}
__global__ __launch_bounds__(256) void k_scanB(const unsigned* __restrict__ bsum,
                                               unsigned* __restrict__ bpre, int nb) {
    __shared__ unsigned sm[256];
    unsigned t = threadIdx.x;
    unsigned v = (t < (unsigned)nb) ? bsum[t] : 0u;
    sm[t] = v;
    __syncthreads();
    for (unsigned d = 1; d < 256; d <<= 1) {
        unsigned x = (t >= d) ? sm[t - d] : 0u;
        __syncthreads();
        sm[t] += x;
        __syncthreads();
    }
    if (t < (unsigned)nb) bpre[t] = sm[t] - v;    // exclusive
}
__global__ __launch_bounds__(256) void k_scanC(const unsigned* __restrict__ hist,
                                               const unsigned* __restrict__ bpre,
                                               unsigned* __restrict__ offs,
                                               unsigned* __restrict__ cursor, int N) {
    __shared__ unsigned sm[256];
    unsigned t = threadIdx.x;
    unsigned i = blockIdx.x * 256u + t;
    unsigned v = (i < (unsigned)N) ? hist[i] : 0u;
    sm[t] = v;
    __syncthreads();
    for (unsigned d = 1; d < 256; d <<= 1) {
        unsigned x = (t >= d) ? sm[t - d] : 0u;
        __syncthreads();
        sm[t] += x;
        __syncthreads();
    }
    unsigned exc = sm[t] - v + bpre[blockIdx.x];
    if (i < (unsigned)N) { offs[i] = exc; cursor[i] = exc; }
    if (i == (unsigned)N - 1) offs[N] = exc + v;
}

// ---- edge MLP (post-factorization): h = silu(b1 + uv[src] + uv[tgt]); layers 2+3 ----
__global__ __launch_bounds__(256) void k_edge_mlp(
    const float* __restrict__ uv, const int* __restrict__ ei,
    const float* __restrict__ rb1, const float* __restrict__ rw2,
    const float* __restrict__ rb2, const float* __restrict__ rw3,
    const float* __restrict__ rb3,
    const unsigned* __restrict__ act_eid, const unsigned* __restrict__ counters,
    float* __restrict__ rawbuf, unsigned* __restrict__ segmax, int E) {
    __shared__ float w2t[64 * 68];                // rw2 transposed, padded stride
    unsigned cnt = counters[0];
    if (blockIdx.x * 256u >= cnt) return;         // whole block inactive (uniform)
    unsigned tid = threadIdx.x;
#pragma unroll
    for (int q = 0; q < 16; ++q) {
        int i = (int)tid + q * 256;
        w2t[(i & 63) * 68 + (i >> 6)] = rw2[i];
    }
    __syncthreads();
    unsigned grp = blockIdx.x * 256u + tid;
    bool active = grp < cnt;
    unsigned gq = active ? grp : (cnt - 1);
    int e = (int)act_eid[gq];
    int s = ei[e], tg = ei[E + e];
    const float4* ur = reinterpret_cast<const float4*>(uv + (size_t)s * HID);
    const float4* vr = reinterpret_cast<const float4*>(uv + (size_t)tg * HID);
    float4 h0, h1, h2, h3, h4, h5, h6, h7, h8, h9, h10, h11, h12, h13, h14, h15;
    INIT16(rb1);
#define ADDUV(hh, i) { float4 _u = ur[i]; float4 _v = vr[i]; \
    hh.x = hh.x + _u.x + _v.x; hh.y = hh.y + _u.y + _v.y; \
    hh.z = hh.z + _u.z + _v.z; hh.w = hh.w + _u.w + _v.w; }
    ADDUV(h0, 0)  ADDUV(h1, 1)  ADDUV(h2, 2)  ADDUV(h3, 3)
    ADDUV(h4, 4)  ADDUV(h5, 5)  ADDUV(h6, 6)  ADDUV(h7, 7)
    ADDUV(h8, 8)  ADDUV(h9, 9)  ADDUV(h10, 10) ADDUV(h11, 11)
    ADDUV(h12, 12) ADDUV(h13, 13) ADDUV(h14, 14) ADDUV(h15, 15)
#undef ADDUV
    SILU16();
    // layers 2+3 fused: per j, dot(h, rw2T[j]) -> silu -> raw += h2*rw3[j]
    float raw = rb3[0];
#pragma unroll 1
    for (int j = 0; j < HID; ++j) {
        const float4* w4 = reinterpret_cast<const float4*>(w2t + j * 68);
        float s0 = rb2[j], s1 = 0.f, s2 = 0.f, s3 = 0.f;
        FD16(w4);
        float h2v = silu_f((s0 + s1) + (s2 + s3));
        raw = fmaf(h2v, rw3[j], raw);
    }
    if (active) {
        rawbuf[grp] = raw;
        atomicMax(&segmax[s], fenc(raw));
    }
}

__global__ void k_exp(const int* __restrict__ ei, const unsigned* __restrict__ act_eid,
                      const unsigned* __restrict__ counters, const unsigned* __restrict__ segmax,
                      float* __restrict__ rawbuf, float* __restrict__ denom, int E) {
    unsigned t = blockIdx.x * blockDim.x + threadIdx.x;
    if (blockIdx.x * blockDim.x >= counters[0]) return;
    if (t >= counters[0]) return;
    int e = (int)act_eid[t];
    int s = ei[e];
    float ev = expf(rawbuf[t] - fdec(segmax[s]));
    rawbuf[t] = ev;
    atomicAdd(&denom[s], ev);
}

// bucket by target with final weight + src pre-packed (coalesced streams for gather)
__global__ void k_fill(const int* __restrict__ ei, const unsigned* __restrict__ act_eid,
                       const unsigned* __restrict__ counters, const float* __restrict__ rawbuf,
                       const float* __restrict__ denom, unsigned* __restrict__ cursor,
                       float* __restrict__ wbuf, unsigned* __restrict__ sbuf, int E) {
    unsigned t = blockIdx.x * blockDim.x + threadIdx.x;
    if (blockIdx.x * blockDim.x >= counters[0]) return;
    if (t >= counters[0]) return;
    int e = (int)act_eid[t];
    int s = ei[e], tg = ei[E + e];
    float w = rawbuf[t] / denom[s];
    unsigned pos = atomicAdd(&cursor[tg], 1u);
    wbuf[pos] = w;
    sbuf[pos] = (unsigned)s;
}

// wave per node: out[n] = states[n] + sum_{incoming active} w * states[src]
__global__ __launch_bounds__(256) void k_gather(
    const float* __restrict__ states, const float* __restrict__ wbuf,
    const unsigned* __restrict__ sbuf, const unsigned* __restrict__ offs,
    float* __restrict__ out, int N) {
    unsigned n = blockIdx.x * 4u + (threadIdx.x >> 6);
    unsigned lane = threadIdx.x & 63u;
    if (n >= (unsigned)N) return;
    unsigned start = offs[n], end = offs[n + 1];
    float2 acc = reinterpret_cast<const float2*>(states + (size_t)n * D)[lane];
    for (unsigned i = start; i < end; ++i) {
        float w = wbuf[i];
        unsigned s = sbuf[i];
        float2 sv = reinterpret_cast<const float2*>(states + (size_t)s * D)[lane];
        acc.x = fmaf(w, sv.x, acc.x);
        acc.y = fmaf(w, sv.y, acc.y);
    }
    reinterpret_cast<float2*>(out + (size_t)n * D)[lane] = acc;
}

// failed nodes: out = tanh(states @ tw + tb) * 0.05
__global__ __launch_bounds__(256) void k_jump(
    const float* __restrict__ states,
    const float* __restrict__ tw, const float* __restrict__ tb,
    const unsigned* __restrict__ mlist, const unsigned* __restrict__ counters,
    float* __restrict__ out) {
    __shared__ float xs[8][D];
    unsigned cnt = counters[1];
    unsigned base = blockIdx.x * 8u;
    if (base >= cnt || cnt == 0) return;          // uniform
    unsigned tid = threadIdx.x;
    unsigned d = tid & 127u, r = tid >> 7;        // r in {0,1}
    {   // stage 8 rows (clamped): 32 threads per row, float4 each
        unsigned j = tid >> 5;
        unsigned c = (tid & 31u) * 4u;
        unsigned slot = base + j; if (slot >= cnt) slot = cnt - 1;
        int nn = (int)mlist[slot];
        *reinterpret_cast<float4*>(&xs[j][c]) =
            *reinterpret_cast<const float4*>(&states[(size_t)nn * D + c]);
    }
    __syncthreads();
    float tbd = tb[d];
    float a0 = tbd, a1 = tbd, a2 = tbd, a3 = tbd;
    const float* x0 = &xs[r * 4 + 0][0];
    const float* x1 = &xs[r * 4 + 1][0];
    const float* x2 = &xs[r * 4 + 2][0];
    const float* x3 = &xs[r * 4 + 3][0];
#pragma unroll 1
    for (int k = 0; k < D; ++k) {
        float w = tw[(size_t)k * D + d];
        a0 = fmaf(x0[k], w, a0);
        a1 = fmaf(x1[k], w, a1);
        a2 = fmaf(x2[k], w, a2);
        a3 = fmaf(x3[k], w, a3);
    }
    float res[4] = {a0, a1, a2, a3};
#pragma unroll
    for (int j2 = 0; j2 < 4; ++j2) {
        unsigned slot = base + r * 4 + j2;
        if (slot < cnt) {
            int nn = (int)mlist[slot];
            out[(size_t)nn * D + d] = tanhf(res[j2]) * 0.05f;
        }
    }
}

extern "C" void kernel_launch(void* const* d_in, const int* in_sizes, int n_in,
                              void* d_out, int out_size, void* d_ws, size_t ws_size,
                              hipStream_t stream) {
    const float* states = (const float*)d_in[0];
    const float* caps   = (const float*)d_in[1];
    const int*   ei     = (const int*)d_in[2];
    const float* rw1 = (const float*)d_in[3];  const float* rb1 = (const float*)d_in[4];
    const float* rw2 = (const float*)d_in[5];  const float* rb2 = (const float*)d_in[6];
    const float* rw3 = (const float*)d_in[7];  const float* rb3 = (const float*)d_in[8];
    const float* pw1 = (const float*)d_in[9];  const float* pb1 = (const float*)d_in[10];
    const float* pw2 = (const float*)d_in[11]; const float* pb2 = (const float*)d_in[12];
    const float* tw  = (const float*)d_in[13]; const float* tb  = (const float*)d_in[14];
    const int N = in_sizes[1];
    const int E = in_sizes[2] / 2;
    float* out = (float*)d_out;
    const int nb = (N + 255) / 256;

    // uv lives in d_out[0 : N*HID) — dead scratch until k_gather/k_jump write out.
    float* uv = out;

    // ws layout (u32 units):
    // [0..3] counters | segmax N | denom N | hist N | mask N | mlist N |
    // offs N+1 | cursor N | bsum 256 | bpre 256 | act_eid E | rawbuf E | wbuf E | sbuf E
    unsigned* ws       = (unsigned*)d_ws;
    unsigned* counters = ws;
    unsigned* segmax   = ws + 4;
    float*    denom    = (float*)(ws + 4 + 1 * (size_t)N);
    unsigned* hist     = ws + 4 + 2 * (size_t)N;
    unsigned* mask     = ws + 4 + 3 * (size_t)N;
    unsigned* mlist    = ws + 4 + 4 * (size_t)N;
    unsigned* offs     = ws + 4 + 5 * (size_t)N;
    unsigned* cursor   = ws + 4 + 6 * (size_t)N + 1;
    unsigned* bsum     = ws + 4 + 7 * (size_t)N + 1;
    unsigned* bpre     = bsum + 256;
    unsigned* act_eid  = bpre + 256;
    float*    rawbuf   = (float*)(act_eid + (size_t)E);
    float*    wbuf     = (float*)(act_eid + 2 * (size_t)E);
    unsigned* sbuf     = act_eid + 3 * (size_t)E;

    // zero counters + segmax + denom + hist (contiguous prefix)
    (void)hipMemsetAsync(d_ws, 0, (size_t)(4 + 3 * (size_t)N) * 4, stream);

    k_protect<<<(N + 63) / 64, 256, 0, stream>>>(states, caps, pw1, pb1, pw2, pb2,
                                                 mask, mlist, counters, out + (size_t)N * D, N);
    k_nodemlp<<<(N + 63) / 64, 256, 0, stream>>>(states, mask, rw1, uv, N);
    k_compact<<<(E + 255) / 256, 256, 0, stream>>>(ei, mask, act_eid, counters, hist, E);
    k_scanA<<<nb, 256, 0, stream>>>(hist, bsum, N);
    k_scanB<<<1, 256, 0, stream>>>(bsum, bpre, nb);
    k_scanC<<<nb, 256, 0, stream>>>(hist, bpre, offs, cursor, N);
    k_edge_mlp<<<(E + 255) / 256, 256, 0, stream>>>(uv, ei, rb1, rw2, rb2, rw3, rb3,
                                                    act_eid, counters, rawbuf, segmax, E);
    k_exp<<<(E + 255) / 256, 256, 0, stream>>>(ei, act_eid, counters, segmax, rawbuf, denom, E);
    k_fill<<<(E + 255) / 256, 256, 0, stream>>>(ei, act_eid, counters, rawbuf, denom,
                                                cursor, wbuf, sbuf, E);
    k_gather<<<(N + 3) / 4, 256, 0, stream>>>(states, wbuf, sbuf, offs, out, N);
    k_jump<<<(N + 7) / 8, 256, 0, stream>>>(states, tw, tb, mlist, counters, out);
}

// Round 12
// 267.122 us; speedup vs baseline: 2.1664x; 1.3999x over previous
//
#include <hip/hip_runtime.h>
#include <cmath>

#define D 128
#define HID 64

__device__ __forceinline__ float silu_f(float x) { return x / (1.0f + expf(-x)); }

__device__ __forceinline__ float4 fma4(float a, float4 w, float4 c) {
    c.x = fmaf(a, w.x, c.x); c.y = fmaf(a, w.y, c.y);
    c.z = fmaf(a, w.z, c.z); c.w = fmaf(a, w.w, c.w);
    return c;
}
__device__ __forceinline__ float4 silu4(float4 v) {
    v.x = silu_f(v.x); v.y = silu_f(v.y); v.z = silu_f(v.z); v.w = silu_f(v.w);
    return v;
}

// order-preserving float <-> uint encode for atomicMax on floats
__device__ __forceinline__ unsigned fenc(float f) {
    unsigned u = __float_as_uint(f);
    return (u & 0x80000000u) ? ~u : (u | 0x80000000u);
}
__device__ __forceinline__ float fdec(unsigned e) {
    unsigned u = (e & 0x80000000u) ? (e & 0x7FFFFFFFu) : ~e;
    return __uint_as_float(u);
}

#define INIT16(bp) { const float4* _b4 = reinterpret_cast<const float4*>(bp); \
    h0 = _b4[0]; h1 = _b4[1]; h2 = _b4[2]; h3 = _b4[3]; \
    h4 = _b4[4]; h5 = _b4[5]; h6 = _b4[6]; h7 = _b4[7]; \
    h8 = _b4[8]; h9 = _b4[9]; h10 = _b4[10]; h11 = _b4[11]; \
    h12 = _b4[12]; h13 = _b4[13]; h14 = _b4[14]; h15 = _b4[15]; }

#define SILU16() { h0 = silu4(h0); h1 = silu4(h1); h2 = silu4(h2); h3 = silu4(h3); \
    h4 = silu4(h4); h5 = silu4(h5); h6 = silu4(h6); h7 = silu4(h7); \
    h8 = silu4(h8); h9 = silu4(h9); h10 = silu4(h10); h11 = silu4(h11); \
    h12 = silu4(h12); h13 = silu4(h13); h14 = silu4(h14); h15 = silu4(h15); }

// dot with 4 partial sums, k%4 -> s0..s3 (matches r1/r2 ordering)
__device__ __forceinline__ void fd4(float4 h, float4 w, float& s0, float& s1, float& s2, float& s3) {
    s0 = fmaf(h.x, w.x, s0); s1 = fmaf(h.y, w.y, s1);
    s2 = fmaf(h.z, w.z, s2); s3 = fmaf(h.w, w.w, s3);
}
#define FD16(w4) { fd4(h0, w4[0], s0, s1, s2, s3);  fd4(h1, w4[1], s0, s1, s2, s3);  \
    fd4(h2, w4[2], s0, s1, s2, s3);  fd4(h3, w4[3], s0, s1, s2, s3);  \
    fd4(h4, w4[4], s0, s1, s2, s3);  fd4(h5, w4[5], s0, s1, s2, s3);  \
    fd4(h6, w4[6], s0, s1, s2, s3);  fd4(h7, w4[7], s0, s1, s2, s3);  \
    fd4(h8, w4[8], s0, s1, s2, s3);  fd4(h9, w4[9], s0, s1, s2, s3);  \
    fd4(h10, w4[10], s0, s1, s2, s3); fd4(h11, w4[11], s0, s1, s2, s3); \
    fd4(h12, w4[12], s0, s1, s2, s3); fd4(h13, w4[13], s0, s1, s2, s3); \
    fd4(h14, w4[14], s0, s1, s2, s3); fd4(h15, w4[15], s0, s1, s2, s3); }

// serial silu-dot over 4 units
__device__ __forceinline__ float accdot(float4 h, float4 w, float act) {
    act = fmaf(silu_f(h.x), w.x, act);
    act = fmaf(silu_f(h.y), w.y, act);
    act = fmaf(silu_f(h.z), w.z, act);
    act = fmaf(silu_f(h.w), w.w, act);
    return act;
}

// ---- protection net: 4 lanes/node split-hid, full pw1 in LDS, 64 nodes/block ----
__global__ __launch_bounds__(256) void k_protect(
    const float* __restrict__ states, const float* __restrict__ caps,
    const float* __restrict__ pw1, const float* __restrict__ pb1,
    const float* __restrict__ pw2, const float* __restrict__ pb2,
    unsigned* __restrict__ mask, unsigned* __restrict__ mlist,
    unsigned* __restrict__ counters, float* __restrict__ outmask, int N) {
    __shared__ float wl[129 * 64];                // 33 KB: all of pw1 (incl. capacity row)
    unsigned tid = threadIdx.x;
    {   // stage 8256 floats = 2064 float4, coalesced
        const float4* s4 = reinterpret_cast<const float4*>(pw1);
        float4* d4 = reinterpret_cast<float4*>(wl);
#pragma unroll
        for (int q = 0; q < 9; ++q) {
            unsigned idx = tid + q * 256u;
            if (idx < 2064u) d4[idx] = s4[idx];
        }
    }
    __syncthreads();
    unsigned nl = tid >> 2, g = tid & 3u;         // lane g owns hidden units [g*16, g*16+16)
    unsigned n = blockIdx.x * 64u + nl;
    bool active = n < (unsigned)N;
    unsigned nq = active ? n : (unsigned)(N - 1);
    const float4* row = reinterpret_cast<const float4*>(states + (size_t)nq * D);
    float4 a0, a1, a2, a3;
    { const float4* b4 = reinterpret_cast<const float4*>(pb1 + g * 16);
      a0 = b4[0]; a1 = b4[1]; a2 = b4[2]; a3 = b4[3]; }
    const float* wg = wl + g * 16;
#pragma unroll 1
    for (int kb = 0; kb < 32; ++kb) {
        float4 x = row[kb];
        const float* w = wg + (size_t)kb * 4 * HID;
        const float4* w0 = reinterpret_cast<const float4*>(w);
        const float4* w1 = reinterpret_cast<const float4*>(w + HID);
        const float4* w2q = reinterpret_cast<const float4*>(w + 2 * HID);
        const float4* w3q = reinterpret_cast<const float4*>(w + 3 * HID);
        a0 = fma4(x.x, w0[0], a0); a1 = fma4(x.x, w0[1], a1); a2 = fma4(x.x, w0[2], a2); a3 = fma4(x.x, w0[3], a3);
        a0 = fma4(x.y, w1[0], a0); a1 = fma4(x.y, w1[1], a1); a2 = fma4(x.y, w1[2], a2); a3 = fma4(x.y, w1[3], a3);
        a0 = fma4(x.z, w2q[0], a0); a1 = fma4(x.z, w2q[1], a1); a2 = fma4(x.z, w2q[2], a2); a3 = fma4(x.z, w2q[3], a3);
        a0 = fma4(x.w, w3q[0], a0); a1 = fma4(x.w, w3q[1], a1); a2 = fma4(x.w, w3q[2], a2); a3 = fma4(x.w, w3q[3], a3);
    }
    {   // capacity row (input dim 128)
        float xv = caps[nq];
        const float4* wc = reinterpret_cast<const float4*>(wg + (size_t)128 * HID);
        a0 = fma4(xv, wc[0], a0); a1 = fma4(xv, wc[1], a1);
        a2 = fma4(xv, wc[2], a2); a3 = fma4(xv, wc[3], a3);
    }
    // layer-2 partial over this lane's 16 units, then 4-lane butterfly reduce
    const float4* w2 = reinterpret_cast<const float4*>(pw2 + g * 16);
    float p = 0.0f;
    p = accdot(a0, w2[0], p); p = accdot(a1, w2[1], p);
    p = accdot(a2, w2[2], p); p = accdot(a3, w2[3], p);
    p += __shfl_xor(p, 1);
    p += __shfl_xor(p, 2);
    // mask decision + wave-aggregated append to mlist (one atomic per wave)
    bool pred = false;
    if (active && g == 0) {
        float act = p + pb2[0];
        unsigned m = (act > 0.0f) ? 1u : 0u;
        mask[n] = m;
        outmask[n] = m ? 1.0f : 0.0f;
        pred = (m != 0u);
    }
    unsigned lane = tid & 63u;
    unsigned long long bal = __ballot(pred);
    unsigned wcnt = (unsigned)__popcll(bal);
    unsigned pre  = (unsigned)__popcll(bal & ((1ull << lane) - 1ull));
    unsigned base = 0;
    if (lane == 0 && wcnt) base = atomicAdd(&counters[1], wcnt);
    base = __shfl(base, 0);
    if (pred) mlist[base + pre] = n;
}

// ---- per-node layer-1 factorization: uv[n] = (mask ? W1a : W1b) @ states[n] ----
__global__ __launch_bounds__(256) void k_nodemlp(
    const float* __restrict__ states, const unsigned* __restrict__ mask,
    const float* __restrict__ rw1, float* __restrict__ uv, int N) {
    __shared__ float wl[16384];                   // 64 KB: W1a (8192) | W1b (8192)
    unsigned tid = threadIdx.x;
    {   // stage all of rw1: 4096 float4, coalesced
        const float4* s4 = reinterpret_cast<const float4*>(rw1);
        float4* d4 = reinterpret_cast<float4*>(wl);
#pragma unroll
        for (int q = 0; q < 16; ++q) d4[tid + q * 256u] = s4[tid + q * 256u];
    }
    __syncthreads();
    unsigned nl = tid >> 2, g = tid & 3u;
    unsigned n = blockIdx.x * 64u + nl;
    if (n >= (unsigned)N) return;
    const float4* row = reinterpret_cast<const float4*>(states + (size_t)n * D);
    unsigned m = mask[n];
    const float* wg = wl + (m ? 0u : 8192u) + g * 16;
    float4 a0, a1, a2, a3;
    a0.x=a0.y=a0.z=a0.w=0.f; a1=a0; a2=a0; a3=a0;
#pragma unroll 1
    for (int kb = 0; kb < 32; ++kb) {
        float4 x = row[kb];
        const float* w = wg + (size_t)kb * 4 * HID;
        const float4* w0 = reinterpret_cast<const float4*>(w);
        const float4* w1 = reinterpret_cast<const float4*>(w + HID);
        const float4* w2q = reinterpret_cast<const float4*>(w + 2 * HID);
        const float4* w3q = reinterpret_cast<const float4*>(w + 3 * HID);
        a0 = fma4(x.x, w0[0], a0); a1 = fma4(x.x, w0[1], a1); a2 = fma4(x.x, w0[2], a2); a3 = fma4(x.x, w0[3], a3);
        a0 = fma4(x.y, w1[0], a0); a1 = fma4(x.y, w1[1], a1); a2 = fma4(x.y, w1[2], a2); a3 = fma4(x.y, w1[3], a3);
        a0 = fma4(x.z, w2q[0], a0); a1 = fma4(x.z, w2q[1], a1); a2 = fma4(x.z, w2q[2], a2); a3 = fma4(x.z, w2q[3], a3);
        a0 = fma4(x.w, w3q[0], a0); a1 = fma4(x.w, w3q[1], a1); a2 = fma4(x.w, w3q[2], a2); a3 = fma4(x.w, w3q[3], a3);
    }
    float4* o = reinterpret_cast<float4*>(uv + (size_t)n * HID + g * 16);
    o[0] = a0; o[1] = a1; o[2] = a2; o[3] = a3;
}

// compact edges with emask = mask[src] && !mask[tgt]; block-aggregated slot alloc
__global__ __launch_bounds__(256) void k_compact(
    const int* __restrict__ ei, const unsigned* __restrict__ mask,
    unsigned* __restrict__ act_eid, unsigned* __restrict__ counters,
    unsigned* __restrict__ hist, int E) {
    __shared__ unsigned wbase[4];
    int e = blockIdx.x * 256 + threadIdx.x;
    unsigned wid = threadIdx.x >> 6, lane = threadIdx.x & 63u;
    bool pred = false; int t = 0;
    if (e < E) {
        int s = ei[e]; t = ei[E + e];
        pred = mask[s] && !mask[t];
    }
    unsigned long long bal = __ballot(pred);
    unsigned wcnt = (unsigned)__popcll(bal);
    unsigned pre  = (unsigned)__popcll(bal & ((1ull << lane) - 1ull));
    if (lane == 0) wbase[wid] = wcnt;
    __syncthreads();
    if (threadIdx.x == 0) {
        unsigned c0 = wbase[0], c1 = wbase[1], c2 = wbase[2], c3 = wbase[3];
        unsigned tot = c0 + c1 + c2 + c3;
        unsigned b = tot ? atomicAdd(&counters[0], tot) : 0u;
        wbase[0] = b; wbase[1] = b + c0; wbase[2] = b + c0 + c1; wbase[3] = b + c0 + c1 + c2;
    }
    __syncthreads();
    if (pred) {
        act_eid[wbase[wid] + pre] = (unsigned)e;
        atomicAdd(&hist[t], 1u);
    }
}

// --- hierarchical exclusive scan of hist[N] -> offs[N+1], cursor[N] ---
__global__ __launch_bounds__(256) void k_scanA(const unsigned* __restrict__ hist,
                                               unsigned* __restrict__ bsum, int N) {
    __shared__ unsigned sm[256];
    unsigned t = threadIdx.x;
    unsigned i = blockIdx.x * 256u + t;
    sm[t] = (i < (unsigned)N) ? hist[i] : 0u;
    __syncthreads();
#pragma unroll
    for (unsigned d = 128; d > 0; d >>= 1) {
        if (t < d) sm[t] += sm[t + d];
        __syncthreads();
    }
    if (t == 0) bsum[blockIdx.x] = sm[0];
}
__global__ __launch_bounds__(256) void k_scanB(const unsigned* __restrict__ bsum,
                                               unsigned* __restrict__ bpre, int nb) {
    __shared__ unsigned sm[256];
    unsigned t = threadIdx.x;
    unsigned v = (t < (unsigned)nb) ? bsum[t] : 0u;
    sm[t] = v;
    __syncthreads();
    for (unsigned d = 1; d < 256; d <<= 1) {
        unsigned x = (t >= d) ? sm[t - d] : 0u;
        __syncthreads();
        sm[t] += x;
        __syncthreads();
    }
    if (t < (unsigned)nb) bpre[t] = sm[t] - v;    // exclusive
}
__global__ __launch_bounds__(256) void k_scanC(const unsigned* __restrict__ hist,
                                               const unsigned* __restrict__ bpre,
                                               unsigned* __restrict__ offs,
                                               unsigned* __restrict__ cursor, int N) {
    __shared__ unsigned sm[256];
    unsigned t = threadIdx.x;
    unsigned i = blockIdx.x * 256u + t;
    unsigned v = (i < (unsigned)N) ? hist[i] : 0u;
    sm[t] = v;
    __syncthreads();
    for (unsigned d = 1; d < 256; d <<= 1) {
        unsigned x = (t >= d) ? sm[t - d] : 0u;
        __syncthreads();
        sm[t] += x;
        __syncthreads();
    }
    unsigned exc = sm[t] - v + bpre[blockIdx.x];
    if (i < (unsigned)N) { offs[i] = exc; cursor[i] = exc; }
    if (i == (unsigned)N - 1) offs[N] = exc + v;
}

// ---- edge MLP (post-factorization): h = silu(b1 + uv[src] + uv[tgt]); layers 2+3 ----
__global__ __launch_bounds__(256) void k_edge_mlp(
    const float* __restrict__ uv, const int* __restrict__ ei,
    const float* __restrict__ rb1, const float* __restrict__ rw2,
    const float* __restrict__ rb2, const float* __restrict__ rw3,
    const float* __restrict__ rb3,
    const unsigned* __restrict__ act_eid, const unsigned* __restrict__ counters,
    float* __restrict__ rawbuf, unsigned* __restrict__ segmax, int E) {
    __shared__ float w2t[64 * 68];                // rw2 transposed, padded stride
    unsigned cnt = counters[0];
    if (blockIdx.x * 256u >= cnt) return;         // whole block inactive (uniform)
    unsigned tid = threadIdx.x;
#pragma unroll
    for (int q = 0; q < 16; ++q) {
        int i = (int)tid + q * 256;
        w2t[(i & 63) * 68 + (i >> 6)] = rw2[i];
    }
    __syncthreads();
    unsigned grp = blockIdx.x * 256u + tid;
    bool active = grp < cnt;
    unsigned gq = active ? grp : (cnt - 1);
    int e = (int)act_eid[gq];
    int s = ei[e], tg = ei[E + e];
    const float4* ur = reinterpret_cast<const float4*>(uv + (size_t)s * HID);
    const float4* vr = reinterpret_cast<const float4*>(uv + (size_t)tg * HID);
    float4 h0, h1, h2, h3, h4, h5, h6, h7, h8, h9, h10, h11, h12, h13, h14, h15;
    INIT16(rb1);
#define ADDUV(hh, i) { float4 _u = ur[i]; float4 _v = vr[i]; \
    hh.x = hh.x + _u.x + _v.x; hh.y = hh.y + _u.y + _v.y; \
    hh.z = hh.z + _u.z + _v.z; hh.w = hh.w + _u.w + _v.w; }
    ADDUV(h0, 0)  ADDUV(h1, 1)  ADDUV(h2, 2)  ADDUV(h3, 3)
    ADDUV(h4, 4)  ADDUV(h5, 5)  ADDUV(h6, 6)  ADDUV(h7, 7)
    ADDUV(h8, 8)  ADDUV(h9, 9)  ADDUV(h10, 10) ADDUV(h11, 11)
    ADDUV(h12, 12) ADDUV(h13, 13) ADDUV(h14, 14) ADDUV(h15, 15)
#undef ADDUV
    SILU16();
    // layers 2+3 fused: per j, dot(h, rw2T[j]) -> silu -> raw += h2*rw3[j]
    float raw = rb3[0];
#pragma unroll 1
    for (int j = 0; j < HID; ++j) {
        const float4* w4 = reinterpret_cast<const float4*>(w2t + j * 68);
        float s0 = rb2[j], s1 = 0.f, s2 = 0.f, s3 = 0.f;
        FD16(w4);
        float h2v = silu_f((s0 + s1) + (s2 + s3));
        raw = fmaf(h2v, rw3[j], raw);
    }
    if (active) {
        rawbuf[grp] = raw;
        atomicMax(&segmax[s], fenc(raw));
    }
}

__global__ void k_exp(const int* __restrict__ ei, const unsigned* __restrict__ act_eid,
                      const unsigned* __restrict__ counters, const unsigned* __restrict__ segmax,
                      float* __restrict__ rawbuf, float* __restrict__ denom, int E) {
    unsigned t = blockIdx.x * blockDim.x + threadIdx.x;
    if (blockIdx.x * blockDim.x >= counters[0]) return;
    if (t >= counters[0]) return;
    int e = (int)act_eid[t];
    int s = ei[e];
    float ev = expf(rawbuf[t] - fdec(segmax[s]));
    rawbuf[t] = ev;
    atomicAdd(&denom[s], ev);
}

// bucket by target with final weight + src pre-packed (coalesced streams for gather)
__global__ void k_fill(const int* __restrict__ ei, const unsigned* __restrict__ act_eid,
                       const unsigned* __restrict__ counters, const float* __restrict__ rawbuf,
                       const float* __restrict__ denom, unsigned* __restrict__ cursor,
                       float* __restrict__ wbuf, unsigned* __restrict__ sbuf, int E) {
    unsigned t = blockIdx.x * blockDim.x + threadIdx.x;
    if (blockIdx.x * blockDim.x >= counters[0]) return;
    if (t >= counters[0]) return;
    int e = (int)act_eid[t];
    int s = ei[e], tg = ei[E + e];
    float w = rawbuf[t] / denom[s];
    unsigned pos = atomicAdd(&cursor[tg], 1u);
    wbuf[pos] = w;
    sbuf[pos] = (unsigned)s;
}

// wave per node: out[n] = states[n] + sum_{incoming active} w * states[src]
__global__ __launch_bounds__(256) void k_gather(
    const float* __restrict__ states, const float* __restrict__ wbuf,
    const unsigned* __restrict__ sbuf, const unsigned* __restrict__ offs,
    float* __restrict__ out, int N) {
    unsigned n = blockIdx.x * 4u + (threadIdx.x >> 6);
    unsigned lane = threadIdx.x & 63u;
    if (n >= (unsigned)N) return;
    unsigned start = offs[n], end = offs[n + 1];
    float2 acc = reinterpret_cast<const float2*>(states + (size_t)n * D)[lane];
    for (unsigned i = start; i < end; ++i) {
        float w = wbuf[i];
        unsigned s = sbuf[i];
        float2 sv = reinterpret_cast<const float2*>(states + (size_t)s * D)[lane];
        acc.x = fmaf(w, sv.x, acc.x);
        acc.y = fmaf(w, sv.y, acc.y);
    }
    reinterpret_cast<float2*>(out + (size_t)n * D)[lane] = acc;
}

// failed nodes: out = tanh(states @ tw + tb) * 0.05
__global__ __launch_bounds__(256) void k_jump(
    const float* __restrict__ states,
    const float* __restrict__ tw, const float* __restrict__ tb,
    const unsigned* __restrict__ mlist, const unsigned* __restrict__ counters,
    float* __restrict__ out) {
    __shared__ float xs[8][D];
    unsigned cnt = counters[1];
    unsigned base = blockIdx.x * 8u;
    if (base >= cnt || cnt == 0) return;          // uniform
    unsigned tid = threadIdx.x;
    unsigned d = tid & 127u, r = tid >> 7;        // r in {0,1}
    {   // stage 8 rows (clamped): 32 threads per row, float4 each
        unsigned j = tid >> 5;
        unsigned c = (tid & 31u) * 4u;
        unsigned slot = base + j; if (slot >= cnt) slot = cnt - 1;
        int nn = (int)mlist[slot];
        *reinterpret_cast<float4*>(&xs[j][c]) =
            *reinterpret_cast<const float4*>(&states[(size_t)nn * D + c]);
    }
    __syncthreads();
    float tbd = tb[d];
    float a0 = tbd, a1 = tbd, a2 = tbd, a3 = tbd;
    const float* x0 = &xs[r * 4 + 0][0];
    const float* x1 = &xs[r * 4 + 1][0];
    const float* x2 = &xs[r * 4 + 2][0];
    const float* x3 = &xs[r * 4 + 3][0];
#pragma unroll 1
    for (int k = 0; k < D; ++k) {
        float w = tw[(size_t)k * D + d];
        a0 = fmaf(x0[k], w, a0);
        a1 = fmaf(x1[k], w, a1);
        a2 = fmaf(x2[k], w, a2);
        a3 = fmaf(x3[k], w, a3);
    }
    float res[4] = {a0, a1, a2, a3};
#pragma unroll
    for (int j2 = 0; j2 < 4; ++j2) {
        unsigned slot = base + r * 4 + j2;
        if (slot < cnt) {
            int nn = (int)mlist[slot];
            out[(size_t)nn * D + d] = tanhf(res[j2]) * 0.05f;
        }
    }
}

extern "C" void kernel_launch(void* const* d_in, const int* in_sizes, int n_in,
                              void* d_out, int out_size, void* d_ws, size_t ws_size,
                              hipStream_t stream) {
    const float* states = (const float*)d_in[0];
    const float* caps   = (const float*)d_in[1];
    const int*   ei     = (const int*)d_in[2];
    const float* rw1 = (const float*)d_in[3];  const float* rb1 = (const float*)d_in[4];
    const float* rw2 = (const float*)d_in[5];  const float* rb2 = (const float*)d_in[6];
    const float* rw3 = (const float*)d_in[7];  const float* rb3 = (const float*)d_in[8];
    const float* pw1 = (const float*)d_in[9];  const float* pb1 = (const float*)d_in[10];
    const float* pw2 = (const float*)d_in[11]; const float* pb2 = (const float*)d_in[12];
    const float* tw  = (const float*)d_in[13]; const float* tb  = (const float*)d_in[14];
    const int N = in_sizes[1];
    const int E = in_sizes[2] / 2;
    float* out = (float*)d_out;
    const int nb = (N + 255) / 256;

    // uv lives in d_out[0 : N*HID) — dead scratch until k_gather/k_jump write out.
    float* uv = out;

    // ws layout (u32 units):
    // [0..3] counters | segmax N | denom N | hist N | mask N | mlist N |
    // offs N+1 | cursor N | bsum 256 | bpre 256 | act_eid E | rawbuf E | wbuf E | sbuf E
    unsigned* ws       = (unsigned*)d_ws;
    unsigned* counters = ws;
    unsigned* segmax   = ws + 4;
    float*    denom    = (float*)(ws + 4 + 1 * (size_t)N);
    unsigned* hist     = ws + 4 + 2 * (size_t)N;
    unsigned* mask     = ws + 4 + 3 * (size_t)N;
    unsigned* mlist    = ws + 4 + 4 * (size_t)N;
    unsigned* offs     = ws + 4 + 5 * (size_t)N;
    unsigned* cursor   = ws + 4 + 6 * (size_t)N + 1;
    unsigned* bsum     = ws + 4 + 7 * (size_t)N + 1;
    unsigned* bpre     = bsum + 256;
    unsigned* act_eid  = bpre + 256;
    float*    rawbuf   = (float*)(act_eid + (size_t)E);
    float*    wbuf     = (float*)(act_eid + 2 * (size_t)E);
    unsigned* sbuf     = act_eid + 3 * (size_t)E;

    // zero counters + segmax + denom + hist (contiguous prefix)
    (void)hipMemsetAsync(d_ws, 0, (size_t)(4 + 3 * (size_t)N) * 4, stream);

    k_protect<<<(N + 63) / 64, 256, 0, stream>>>(states, caps, pw1, pb1, pw2, pb2,
                                                 mask, mlist, counters, out + (size_t)N * D, N);
    k_nodemlp<<<(N + 63) / 64, 256, 0, stream>>>(states, mask, rw1, uv, N);
    k_compact<<<(E + 255) / 256, 256, 0, stream>>>(ei, mask, act_eid, counters, hist, E);
    k_scanA<<<nb, 256, 0, stream>>>(hist, bsum, N);
    k_scanB<<<1, 256, 0, stream>>>(bsum, bpre, nb);
    k_scanC<<<nb, 256, 0, stream>>>(hist, bpre, offs, cursor, N);
    k_edge_mlp<<<(E + 255) / 256, 256, 0, stream>>>(uv, ei, rb1, rw2, rb2, rw3, rb3,
                                                    act_eid, counters, rawbuf, segmax, E);
    k_exp<<<(E + 255) / 256, 256, 0, stream>>>(ei, act_eid, counters, segmax, rawbuf, denom, E);
    k_fill<<<(E + 255) / 256, 256, 0, stream>>>(ei, act_eid, counters, rawbuf, denom,
                                                cursor, wbuf, sbuf, E);
    k_gather<<<(N + 3) / 4, 256, 0, stream>>>(states, wbuf, sbuf, offs, out, N);
    k_jump<<<(N + 7) / 8, 256, 0, stream>>>(states, tw, tb, mlist, counters, out);
}